// Round 2
// baseline (8024.797 us; speedup 1.0000x reference)
//
#include <hip/hip_runtime.h>
#include <math.h>

#define NANG 720
#define NDET 512
#define KPTS (NANG*NDET)        // 368640
#define G 1024
#define GG (G*G)
#define ALPHA_F 14.04f
#define NITER_DCOMP 10
#define HH 512
#define WW 512

// ---------------- workspace layout (byte offsets into d_ws) ----------------
#define O_TW512   0UL                          // 512  double2 (8 KB)
#define O_TW1024  (O_TW512  + 512UL*16)        // 1024 double2 (16 KB)
#define O_DPOD    (O_TW1024 + 1024UL*16)       // 512 f32
#define O_WY      32768UL                      // 6*K f32
#define O_WX      (O_WY  + 6UL*KPTS*4)         // 6*K f32
#define O_IY      (O_WX  + 6UL*KPTS*4)         // 6*K s16
#define O_IX      (O_IY  + 6UL*KPTS*2)         // 6*K s16
#define O_WDC     (O_IX  + 6UL*KPTS*2)         // K f32
#define O_KD      (O_WDC + (size_t)KPTS*4)     // K float2
#define O_GR      (O_KD  + (size_t)KPTS*8)     // GG f32 (real grid, dcomp)
#define O_GC      (O_GR  + (size_t)GG*4)       // GG float2 (complex grid)
#define O_W1      (O_GC  + (size_t)GG*8)       // 512*1024 float2 (pass1 out, [q][r])
// total ~45.6 MB

// ---------------- modified Bessel I0 (Abramowitz-Stegun, rel err ~2e-7) ----
__device__ __forceinline__ float i0f(float x){
  float ax = fabsf(x);
  if (ax < 3.75f){
    float t = ax*(1.0f/3.75f); t *= t;
    return 1.0f + t*(3.5156229f + t*(3.0899424f + t*(1.2067492f +
           t*(0.2659732f + t*(0.0360768f + t*0.0045813f)))));
  } else {
    float t = 3.75f/ax;
    float p = 0.39894228f + t*(0.01328592f + t*(0.00225319f + t*(-0.00157565f +
              t*(0.00916281f + t*(-0.02057706f + t*(0.02635537f +
              t*(-0.01647633f + t*0.00392377f)))))));
    return expf(ax)*rsqrtf(ax)*p;
  }
}

// ---------------- tables: twiddles (f64) + deapodization (f32) -------------
__global__ __launch_bounds__(256) void gen_tables(double2* tw512, double2* tw1024, float* dpod){
  int i = blockIdx.x*blockDim.x + threadIdx.x;
  if (i < 512){
    double ang = -2.0*M_PI*(double)i/512.0;      // forward FFT
    tw512[i] = make_double2(cos(ang), sin(ang));
  }
  if (i < 1024){
    double ang = 2.0*M_PI*(double)i/1024.0;      // inverse FFT
    tw1024[i] = make_double2(cos(ang), sin(ang));
  }
  if (i < 512){
    float n  = (float)i - 256.0f;
    float xi = n * (1.0f/(float)G);
    float a  = (float)M_PI * 6.0f * xi;
    float t  = a*a - ALPHA_F*ALPHA_F;
    float z  = sqrtf(fabsf(t));
    float kbft;
    if (t < 0.0f) kbft = sinhf(z) / fmaxf(z, 1e-12f);
    else          kbft = (z < 1e-12f) ? 1.0f : sinf(z)/z;
    kbft *= 6.0f / i0f(ALPHA_F);
    dpod[i] = 1.0f / kbft;
  }
}

// ---------------- KB weights/indices per point, [j][K] streams -------------
__global__ __launch_bounds__(256) void precompute_kb(const float* __restrict__ ktraj,
    float* __restrict__ wy, float* __restrict__ wx,
    short* __restrict__ iy, short* __restrict__ ix, float* __restrict__ wdc){
  int k = blockIdx.x*blockDim.x + threadIdx.x;
  if (k >= KPTS) return;
  const float gfac = (float)((double)G/(2.0*M_PI));
  const float inv_i0a = 1.0f / i0f(ALPHA_F);
  #pragma unroll
  for (int dim = 0; dim < 2; ++dim){
    float om = ktraj[(size_t)dim*KPTS + k];
    float gx = om * gfac;
    int k0 = (int)floorf(gx);
    #pragma unroll
    for (int j = 0; j < 6; ++j){
      int idx = k0 + (j - 2);
      float d = gx - (float)idx;
      float u = (2.0f*d)*(1.0f/6.0f);
      float t = 1.0f - u*u;
      float w = 0.0f;
      if (t > 0.0f) w = i0f(ALPHA_F * sqrtf(fmaxf(t, 1e-20f))) * inv_i0a;
      short im = (short)((idx + 2048) & (G-1));
      if (dim == 0){ wy[j*KPTS + k] = w; iy[j*KPTS + k] = im; }
      else         { wx[j*KPTS + k] = w; ix[j*KPTS + k] = im; }
    }
  }
  wdc[k] = 1.0f;
}

// ---------------- 512-pt row DFT with fftshifts (f64 accum) ----------------
__global__ __launch_bounds__(256) void rowfft(const float* __restrict__ sino,
    const double2* __restrict__ tw512g, float2* __restrict__ kd){
  __shared__ float   srow[NDET];
  __shared__ double2 tw[NDET];
  int a = blockIdx.x;
  for (int i = threadIdx.x; i < NDET; i += blockDim.x){
    srow[i] = sino[(size_t)a*NDET + i];
    tw[i]   = tw512g[i];
  }
  __syncthreads();
  int k0 = threadIdx.x, k1 = threadIdx.x + 256;
  int kp0 = (k0 + 256) & 511, kp1 = (k1 + 256) & 511;
  double ar0=0, ai0=0, ar1=0, ai1=0;
  for (int n = 0; n < NDET; ++n){
    float s = srow[(n + 256) & 511];
    double2 t0 = tw[(n*kp0) & 511];
    double2 t1 = tw[(n*kp1) & 511];
    ar0 += s*t0.x; ai0 += s*t0.y;
    ar1 += s*t1.x; ai1 += s*t1.y;
  }
  kd[(size_t)a*NDET + k0] = make_float2((float)ar0, (float)ai0);
  kd[(size_t)a*NDET + k1] = make_float2((float)ar1, (float)ai1);
}

// ---------------- dcomp: real scatter / gather+divide ----------------------
__global__ __launch_bounds__(256) void scatter_real(const float* __restrict__ wdc,
    const float* __restrict__ wy, const float* __restrict__ wx,
    const short* __restrict__ iy, const short* __restrict__ ix,
    float* __restrict__ grid){
  int k = blockIdx.x*blockDim.x + threadIdx.x;
  if (k >= KPTS) return;
  float val = wdc[k];
  float wyv[6], wxv[6]; int iyv[6], ixv[6];
  #pragma unroll
  for (int j = 0; j < 6; ++j){
    wyv[j] = wy[j*KPTS + k] * val;
    wxv[j] = wx[j*KPTS + k];
    iyv[j] = ((int)iy[j*KPTS + k]) << 10;
    ixv[j] = (int)ix[j*KPTS + k];
  }
  #pragma unroll
  for (int j = 0; j < 6; ++j){
    #pragma unroll
    for (int i = 0; i < 6; ++i){
      atomicAdd(grid + (iyv[j] + ixv[i]), wyv[j]*wxv[i]);
    }
  }
}

__global__ __launch_bounds__(256) void gather_div(
    const float* __restrict__ wy, const float* __restrict__ wx,
    const short* __restrict__ iy, const short* __restrict__ ix,
    const float* __restrict__ grid, float* __restrict__ wdc){
  int k = blockIdx.x*blockDim.x + threadIdx.x;
  if (k >= KPTS) return;
  float wyv[6], wxv[6]; int iyv[6], ixv[6];
  #pragma unroll
  for (int j = 0; j < 6; ++j){
    wyv[j] = wy[j*KPTS + k];
    wxv[j] = wx[j*KPTS + k];
    iyv[j] = ((int)iy[j*KPTS + k]) << 10;
    ixv[j] = (int)ix[j*KPTS + k];
  }
  float s = 0.0f;
  #pragma unroll
  for (int j = 0; j < 6; ++j){
    float rs = 0.0f;
    #pragma unroll
    for (int i = 0; i < 6; ++i) rs += grid[iyv[j] + ixv[i]] * wxv[i];
    s += rs * wyv[j];
  }
  wdc[k] = wdc[k] / fmaxf(fabsf(s), 1e-12f);
}

// ---------------- final complex scatter of kd*dc ---------------------------
__global__ __launch_bounds__(256) void scatter_cplx(const float2* __restrict__ kd,
    const float* __restrict__ wdc,
    const float* __restrict__ wy, const float* __restrict__ wx,
    const short* __restrict__ iy, const short* __restrict__ ix,
    float* __restrict__ gridc){
  int k = blockIdx.x*blockDim.x + threadIdx.x;
  if (k >= KPTS) return;
  float2 kv = kd[k];
  float dc = wdc[k];
  float vr = kv.x*dc, vi = kv.y*dc;
  float wyv[6], wxv[6]; int iyv[6], ixv[6];
  #pragma unroll
  for (int j = 0; j < 6; ++j){
    wyv[j] = wy[j*KPTS + k];
    wxv[j] = wx[j*KPTS + k];
    iyv[j] = ((int)iy[j*KPTS + k]) << 10;
    ixv[j] = (int)ix[j*KPTS + k];
  }
  #pragma unroll
  for (int j = 0; j < 6; ++j){
    #pragma unroll
    for (int i = 0; i < 6; ++i){
      float ww = wyv[j]*wxv[i];
      int off = (iyv[j] + ixv[i]) * 2;
      atomicAdd(gridc + off,     ww*vr);
      atomicAdd(gridc + off + 1, ww*vi);
    }
  }
}

// ---------------- IFFT pass 1: rows, only 512 needed output cols -----------
__global__ __launch_bounds__(256) void ifft_rows(const float2* __restrict__ gridc,
    const double2* __restrict__ tw1024g, float2* __restrict__ W1T){
  __shared__ float2  row[G];
  __shared__ double2 tw[G];
  int r = blockIdx.x;
  for (int i = threadIdx.x; i < G; i += blockDim.x){
    row[i] = gridc[(size_t)r*G + i];
    tw[i]  = tw1024g[i];
  }
  __syncthreads();
  int q0 = threadIdx.x, q1 = threadIdx.x + 256;
  int m0 = (q0 + 768) & (G-1), m1 = (q1 + 768) & (G-1);
  double ar0=0, ai0=0, ar1=0, ai1=0;
  for (int c = 0; c < G; ++c){
    float2 v = row[c];
    double2 t0 = tw[(c*m0) & (G-1)];
    double2 t1 = tw[(c*m1) & (G-1)];
    ar0 += v.x*t0.x - v.y*t0.y;  ai0 += v.x*t0.y + v.y*t0.x;
    ar1 += v.x*t1.x - v.y*t1.y;  ai1 += v.x*t1.y + v.y*t1.x;
  }
  W1T[(size_t)q0*G + r] = make_float2((float)ar0, (float)ai0);
  W1T[(size_t)q1*G + r] = make_float2((float)ar1, (float)ai1);
}

// ---------------- IFFT pass 2: cols, real part + deapod + crop -------------
__global__ __launch_bounds__(256) void ifft_cols(const float2* __restrict__ W1T,
    const double2* __restrict__ tw1024g, const float* __restrict__ dpod,
    float* __restrict__ out){
  __shared__ float2  col[G];
  __shared__ double2 tw[G];
  int q = blockIdx.x;
  for (int i = threadIdx.x; i < G; i += blockDim.x){
    col[i] = W1T[(size_t)q*G + i];
    tw[i]  = tw1024g[i];
  }
  __syncthreads();
  float dq = dpod[q];
  int p0 = threadIdx.x, p1 = threadIdx.x + 256;
  int m0 = (p0 + 768) & (G-1), m1 = (p1 + 768) & (G-1);
  double ar0=0, ar1=0;
  for (int r = 0; r < G; ++r){
    float2 v = col[r];
    double2 t0 = tw[(r*m0) & (G-1)];
    double2 t1 = tw[(r*m1) & (G-1)];
    ar0 += v.x*t0.x - v.y*t0.y;
    ar1 += v.x*t1.x - v.y*t1.y;
  }
  out[(size_t)p0*WW + q] = (float)ar0 * (1.0f/1024.0f) * dpod[p0] * dq;
  out[(size_t)p1*WW + q] = (float)ar1 * (1.0f/1024.0f) * dpod[p1] * dq;
}

// ---------------------------------------------------------------------------
extern "C" void kernel_launch(void* const* d_in, const int* in_sizes, int n_in,
                              void* d_out, int out_size, void* d_ws, size_t ws_size,
                              hipStream_t stream){
  const float* sino  = (const float*)d_in[0];
  const float* ktraj = (const float*)d_in[1];
  float* out = (float*)d_out;
  char* ws = (char*)d_ws;

  double2* tw512  = (double2*)(ws + O_TW512);
  double2* tw1024 = (double2*)(ws + O_TW1024);
  float*   dpod   = (float*)  (ws + O_DPOD);
  float*   wy     = (float*)  (ws + O_WY);
  float*   wx     = (float*)  (ws + O_WX);
  short*   iy     = (short*)  (ws + O_IY);
  short*   ix     = (short*)  (ws + O_IX);
  float*   wdc    = (float*)  (ws + O_WDC);
  float2*  kd     = (float2*) (ws + O_KD);
  float*   gridR  = (float*)  (ws + O_GR);
  float2*  gridC  = (float2*) (ws + O_GC);
  float2*  W1T    = (float2*) (ws + O_W1);

  const int PB = (KPTS + 255)/256;   // 1440

  gen_tables<<<4, 256, 0, stream>>>(tw512, tw1024, dpod);
  precompute_kb<<<PB, 256, 0, stream>>>(ktraj, wy, wx, iy, ix, wdc);
  rowfft<<<NANG, 256, 0, stream>>>(sino, tw512, kd);

  for (int it = 0; it < NITER_DCOMP; ++it){
    hipMemsetAsync(gridR, 0, (size_t)GG*sizeof(float), stream);
    scatter_real<<<PB, 256, 0, stream>>>(wdc, wy, wx, iy, ix, gridR);
    gather_div<<<PB, 256, 0, stream>>>(wy, wx, iy, ix, gridR, wdc);
  }

  hipMemsetAsync(gridC, 0, (size_t)GG*2*sizeof(float), stream);
  scatter_cplx<<<PB, 256, 0, stream>>>(kd, wdc, wy, wx, iy, ix, (float*)gridC);

  ifft_rows<<<G, 256, 0, stream>>>(gridC, tw1024, W1T);
  ifft_cols<<<WW, 256, 0, stream>>>(W1T, tw1024, dpod, out);
}

// Round 3
// 4105.689 us; speedup vs baseline: 1.9546x; 1.9546x over previous
//
#include <hip/hip_runtime.h>
#include <math.h>

#define NANG 720
#define NDET 512
#define KPTS (NANG*NDET)        // 368640
#define G 1024
#define GG (G*G)
#define ALPHA_F 14.04f
#define NITER_DCOMP 10
#define WW 512

#define CAP 4096                 // max points per scatter chunk
#define PAIR_CAP 1474624         // >= hard worst case 4*KPTS = 1474560
#define NSCATTER_BLOCKS 1536     // >= 1024 + 4*KPTS/CAP = 1384

// ---------------- workspace layout (byte offsets) --------------------------
#define O_TW512   0UL            // 512 double2
#define O_TW1024  8192UL         // 1024 double2
#define O_DPOD    24576UL        // 512 f32
#define O_CNT     32768UL        // 1024 int
#define O_FILL    36864UL        // 1024 int
#define O_START   40960UL        // 1025 int
#define O_NCH     46080UL        // 1 int
#define O_CHUNK   49152UL        // 2048 int4 (32KB)
#define O_REC     131072UL       // KPTS * 64B = 23.6MB   (reused as W1T later)
#define O_PAIRS   (O_REC   + (size_t)KPTS*64)       // PAIR_CAP int = 5.9MB
#define O_WDC     (O_PAIRS + (size_t)PAIR_CAP*4)    // K f32
#define O_KD      (O_WDC   + (size_t)KPTS*4)        // K float2
#define O_GR      (O_KD    + (size_t)KPTS*8)        // GG f32
#define O_GC      (O_GR    + (size_t)GG*4)          // GG float2
// end ~44.5MB

struct __align__(16) PointRec {
  float wy[6];
  float wx[6];
  int   iy0, ix0;
  int   pad0, pad1;   // 64B total
};

// ---------------- modified Bessel I0 (Abramowitz-Stegun) -------------------
__device__ __forceinline__ float i0f(float x){
  float ax = fabsf(x);
  if (ax < 3.75f){
    float t = ax*(1.0f/3.75f); t *= t;
    return 1.0f + t*(3.5156229f + t*(3.0899424f + t*(1.2067492f +
           t*(0.2659732f + t*(0.0360768f + t*0.0045813f)))));
  } else {
    float t = 3.75f/ax;
    float p = 0.39894228f + t*(0.01328592f + t*(0.00225319f + t*(-0.00157565f +
              t*(0.00916281f + t*(-0.02057706f + t*(0.02635537f +
              t*(-0.01647633f + t*0.00392377f)))))));
    return expf(ax)*rsqrtf(ax)*p;
  }
}

// ---------------- tables ---------------------------------------------------
__global__ __launch_bounds__(256) void gen_tables(double2* tw512, double2* tw1024, float* dpod){
  int i = blockIdx.x*blockDim.x + threadIdx.x;
  if (i < 512){
    double ang = -2.0*M_PI*(double)i/512.0;
    tw512[i] = make_double2(cos(ang), sin(ang));
  }
  if (i < 1024){
    double ang = 2.0*M_PI*(double)i/1024.0;
    tw1024[i] = make_double2(cos(ang), sin(ang));
  }
  if (i < 512){
    float n  = (float)i - 256.0f;
    float xi = n * (1.0f/(float)G);
    float a  = (float)M_PI * 6.0f * xi;
    float t  = a*a - ALPHA_F*ALPHA_F;
    float z  = sqrtf(fabsf(t));
    float kbft;
    if (t < 0.0f) kbft = sinhf(z) / fmaxf(z, 1e-12f);
    else          kbft = (z < 1e-12f) ? 1.0f : sinf(z)/z;
    kbft *= 6.0f / i0f(ALPHA_F);
    dpod[i] = 1.0f / kbft;
  }
}

// ---------------- KB records per point -------------------------------------
__global__ __launch_bounds__(256) void precompute_kb(const float* __restrict__ ktraj,
    PointRec* __restrict__ rec, float* __restrict__ wdc){
  int k = blockIdx.x*blockDim.x + threadIdx.x;
  if (k >= KPTS) return;
  const float gfac = (float)((double)G/(2.0*M_PI));
  const float inv_i0a = 1.0f / i0f(ALPHA_F);
  PointRec r;
  #pragma unroll
  for (int dim = 0; dim < 2; ++dim){
    float om = ktraj[(size_t)dim*KPTS + k];
    float gx = om * gfac;
    int k0 = (int)floorf(gx);
    #pragma unroll
    for (int j = 0; j < 6; ++j){
      int idx = k0 + (j - 2);
      float d = gx - (float)idx;
      float u = (2.0f*d)*(1.0f/6.0f);
      float t = 1.0f - u*u;
      float w = 0.0f;
      if (t > 0.0f) w = i0f(ALPHA_F * sqrtf(fmaxf(t, 1e-20f))) * inv_i0a;
      if (dim == 0) r.wy[j] = w; else r.wx[j] = w;
    }
    int i0v = (k0 - 2 + 2048) & (G-1);
    if (dim == 0) r.iy0 = i0v; else r.ix0 = i0v;
  }
  r.pad0 = 0; r.pad1 = 0;
  rec[k] = r;
  wdc[k] = 1.0f;
}

// ---------------- tile list build ------------------------------------------
__device__ __forceinline__ int tiles_of(int iy0, int ix0, int* tl){
  int ty0 = iy0>>5, ty1 = ((iy0+5)&(G-1))>>5;
  int tx0 = ix0>>5, tx1 = ((ix0+5)&(G-1))>>5;
  int n = 0;
  tl[n++] = ty0*32+tx0;
  if (tx1!=tx0) tl[n++] = ty0*32+tx1;
  if (ty1!=ty0){
    tl[n++] = ty1*32+tx0;
    if (tx1!=tx0) tl[n++] = ty1*32+tx1;
  }
  return n;
}

__global__ __launch_bounds__(256) void count_tiles(const PointRec* __restrict__ rec,
    int* __restrict__ cnt){
  int k = blockIdx.x*blockDim.x + threadIdx.x;
  if (k >= KPTS) return;
  int tl[4];
  int n = tiles_of(rec[k].iy0, rec[k].ix0, tl);
  for (int i=0;i<n;i++) atomicAdd(&cnt[tl[i]], 1);
}

__global__ __launch_bounds__(1024) void scan_build(const int* __restrict__ cnt,
    int* __restrict__ tileStart, int4* __restrict__ chunkTbl, int* __restrict__ nChunks){
  __shared__ int s[1024];
  int t = threadIdx.x;
  int c = cnt[t];
  s[t] = c; __syncthreads();
  for (int off=1; off<1024; off<<=1){
    int v = (t>=off) ? s[t-off] : 0;
    __syncthreads();
    s[t] += v;
    __syncthreads();
  }
  int excl = s[t] - c;
  tileStart[t] = excl;
  if (t==1023) tileStart[1024] = s[1023];
  int nch = (c + CAP - 1)/CAP;
  __syncthreads();
  s[t] = nch; __syncthreads();
  for (int off=1; off<1024; off<<=1){
    int v = (t>=off) ? s[t-off] : 0;
    __syncthreads();
    s[t] += v;
    __syncthreads();
  }
  int cbase = s[t] - nch;
  for (int i=0;i<nch;i++)
    chunkTbl[cbase+i] = make_int4(t, excl + i*CAP, min(CAP, c - i*CAP), 0);
  if (t==1023) *nChunks = s[1023];
}

__global__ __launch_bounds__(256) void fill_pairs(const PointRec* __restrict__ rec,
    const int* __restrict__ tileStart, int* __restrict__ fill, int* __restrict__ pairs){
  int k = blockIdx.x*blockDim.x + threadIdx.x;
  if (k >= KPTS) return;
  int tl[4];
  int n = tiles_of(rec[k].iy0, rec[k].ix0, tl);
  for (int i=0;i<n;i++){
    int t = tl[i];
    int pos = atomicAdd(&fill[t], 1);
    pairs[tileStart[t] + pos] = k;
  }
}

// ---------------- 512-pt row DFT with fftshifts (f64 accum) ----------------
__global__ __launch_bounds__(256) void rowfft(const float* __restrict__ sino,
    const double2* __restrict__ tw512g, float2* __restrict__ kd){
  __shared__ float   srow[NDET];
  __shared__ double2 tw[NDET];
  int a = blockIdx.x;
  for (int i = threadIdx.x; i < NDET; i += blockDim.x){
    srow[i] = sino[(size_t)a*NDET + i];
    tw[i]   = tw512g[i];
  }
  __syncthreads();
  int k0 = threadIdx.x, k1 = threadIdx.x + 256;
  int kp0 = (k0 + 256) & 511, kp1 = (k1 + 256) & 511;
  double ar0=0, ai0=0, ar1=0, ai1=0;
  for (int n = 0; n < NDET; ++n){
    float s = srow[(n + 256) & 511];
    double2 t0 = tw[(n*kp0) & 511];
    double2 t1 = tw[(n*kp1) & 511];
    ar0 += s*t0.x; ai0 += s*t0.y;
    ar1 += s*t1.x; ai1 += s*t1.y;
  }
  kd[(size_t)a*NDET + k0] = make_float2((float)ar0, (float)ai0);
  kd[(size_t)a*NDET + k1] = make_float2((float)ar1, (float)ai1);
}

// ---------------- tiled scatter: real (dcomp) ------------------------------
__global__ __launch_bounds__(256) void scatter_real_tiled(
    const int4* __restrict__ chunkTbl, const int* __restrict__ nChunks,
    const int* __restrict__ pairs, const PointRec* __restrict__ rec,
    const float* __restrict__ wdc, float* __restrict__ grid){
  __shared__ float tile[1024];
  int b = blockIdx.x;
  if (b >= *nChunks) return;
  int4 ch = chunkTbl[b];
  int tyc = (ch.x>>5)<<5;     // tile cell origin y
  int txc = (ch.x&31)<<5;     // tile cell origin x
  for (int i = threadIdx.x; i < 1024; i += 256) tile[i] = 0.f;
  __syncthreads();
  for (int p = threadIdx.x; p < ch.z; p += 256){
    int k = pairs[ch.y + p];
    PointRec r = rec[k];
    float val = wdc[k];
    #pragma unroll
    for (int j = 0; j < 6; ++j){
      int y = (r.iy0 + j) & (G-1);
      if ((y & ~31) != tyc) continue;
      float wv = r.wy[j] * val;
      int lb = (y & 31) << 5;
      #pragma unroll
      for (int i2 = 0; i2 < 6; ++i2){
        int x = (r.ix0 + i2) & (G-1);
        if ((x & ~31) != txc) continue;
        atomicAdd(&tile[lb + (x & 31)], wv * r.wx[i2]);
      }
    }
  }
  __syncthreads();
  for (int i = threadIdx.x; i < 1024; i += 256){
    float v = tile[i];
    if (v != 0.f)
      atomicAdd(&grid[((size_t)(tyc + (i>>5)) << 10) + txc + (i & 31)], v);
  }
}

// ---------------- tiled scatter: complex (final grid) ----------------------
__global__ __launch_bounds__(256) void scatter_cplx_tiled(
    const int4* __restrict__ chunkTbl, const int* __restrict__ nChunks,
    const int* __restrict__ pairs, const PointRec* __restrict__ rec,
    const float2* __restrict__ kd, const float* __restrict__ wdc,
    float* __restrict__ gridc){
  __shared__ float tre[1024];
  __shared__ float tim[1024];
  int b = blockIdx.x;
  if (b >= *nChunks) return;
  int4 ch = chunkTbl[b];
  int tyc = (ch.x>>5)<<5;
  int txc = (ch.x&31)<<5;
  for (int i = threadIdx.x; i < 1024; i += 256){ tre[i] = 0.f; tim[i] = 0.f; }
  __syncthreads();
  for (int p = threadIdx.x; p < ch.z; p += 256){
    int k = pairs[ch.y + p];
    PointRec r = rec[k];
    float2 kv = kd[k];
    float dc = wdc[k];
    float vr = kv.x*dc, vi = kv.y*dc;
    #pragma unroll
    for (int j = 0; j < 6; ++j){
      int y = (r.iy0 + j) & (G-1);
      if ((y & ~31) != tyc) continue;
      float wyv = r.wy[j];
      int lb = (y & 31) << 5;
      #pragma unroll
      for (int i2 = 0; i2 < 6; ++i2){
        int x = (r.ix0 + i2) & (G-1);
        if ((x & ~31) != txc) continue;
        float ww = wyv * r.wx[i2];
        int li = lb + (x & 31);
        atomicAdd(&tre[li], ww*vr);
        atomicAdd(&tim[li], ww*vi);
      }
    }
  }
  __syncthreads();
  for (int i = threadIdx.x; i < 1024; i += 256){
    float vr = tre[i], vi = tim[i];
    if (vr != 0.f || vi != 0.f){
      size_t off = (((size_t)(tyc + (i>>5)) << 10) + txc + (i & 31)) * 2;
      atomicAdd(&gridc[off],     vr);
      atomicAdd(&gridc[off + 1], vi);
    }
  }
}

// ---------------- gather + divide (dcomp) ----------------------------------
__global__ __launch_bounds__(256) void gather_div(const PointRec* __restrict__ rec,
    const float* __restrict__ grid, float* __restrict__ wdc){
  int k = blockIdx.x*blockDim.x + threadIdx.x;
  if (k >= KPTS) return;
  PointRec r = rec[k];
  float s = 0.f;
  #pragma unroll
  for (int j = 0; j < 6; ++j){
    int rowb = ((r.iy0 + j) & (G-1)) << 10;
    float rs = 0.f;
    #pragma unroll
    for (int i = 0; i < 6; ++i)
      rs += grid[rowb + ((r.ix0 + i) & (G-1))] * r.wx[i];
    s += rs * r.wy[j];
  }
  wdc[k] = wdc[k] / fmaxf(fabsf(s), 1e-12f);
}

// ---------------- IFFT pass 1: rows ----------------------------------------
__global__ __launch_bounds__(256) void ifft_rows(const float2* __restrict__ gridc,
    const double2* __restrict__ tw1024g, float2* __restrict__ W1T){
  __shared__ float2  row[G];
  __shared__ double2 tw[G];
  int r = blockIdx.x;
  for (int i = threadIdx.x; i < G; i += blockDim.x){
    row[i] = gridc[(size_t)r*G + i];
    tw[i]  = tw1024g[i];
  }
  __syncthreads();
  int q0 = threadIdx.x, q1 = threadIdx.x + 256;
  int m0 = (q0 + 768) & (G-1), m1 = (q1 + 768) & (G-1);
  double ar0=0, ai0=0, ar1=0, ai1=0;
  for (int c = 0; c < G; ++c){
    float2 v = row[c];
    double2 t0 = tw[(c*m0) & (G-1)];
    double2 t1 = tw[(c*m1) & (G-1)];
    ar0 += v.x*t0.x - v.y*t0.y;  ai0 += v.x*t0.y + v.y*t0.x;
    ar1 += v.x*t1.x - v.y*t1.y;  ai1 += v.x*t1.y + v.y*t1.x;
  }
  W1T[(size_t)q0*G + r] = make_float2((float)ar0, (float)ai0);
  W1T[(size_t)q1*G + r] = make_float2((float)ar1, (float)ai1);
}

// ---------------- IFFT pass 2: cols + deapod + crop ------------------------
__global__ __launch_bounds__(256) void ifft_cols(const float2* __restrict__ W1T,
    const double2* __restrict__ tw1024g, const float* __restrict__ dpod,
    float* __restrict__ out){
  __shared__ float2  col[G];
  __shared__ double2 tw[G];
  int q = blockIdx.x;
  for (int i = threadIdx.x; i < G; i += blockDim.x){
    col[i] = W1T[(size_t)q*G + i];
    tw[i]  = tw1024g[i];
  }
  __syncthreads();
  float dq = dpod[q];
  int p0 = threadIdx.x, p1 = threadIdx.x + 256;
  int m0 = (p0 + 768) & (G-1), m1 = (p1 + 768) & (G-1);
  double ar0=0, ar1=0;
  for (int r = 0; r < G; ++r){
    float2 v = col[r];
    double2 t0 = tw[(r*m0) & (G-1)];
    double2 t1 = tw[(r*m1) & (G-1)];
    ar0 += v.x*t0.x - v.y*t0.y;
    ar1 += v.x*t1.x - v.y*t1.y;
  }
  out[(size_t)p0*WW + q] = (float)ar0 * (1.0f/1024.0f) * dpod[p0] * dq;
  out[(size_t)p1*WW + q] = (float)ar1 * (1.0f/1024.0f) * dpod[p1] * dq;
}

// ---------------------------------------------------------------------------
extern "C" void kernel_launch(void* const* d_in, const int* in_sizes, int n_in,
                              void* d_out, int out_size, void* d_ws, size_t ws_size,
                              hipStream_t stream){
  const float* sino  = (const float*)d_in[0];
  const float* ktraj = (const float*)d_in[1];
  float* out = (float*)d_out;
  char* ws = (char*)d_ws;

  double2*  tw512   = (double2*) (ws + O_TW512);
  double2*  tw1024  = (double2*) (ws + O_TW1024);
  float*    dpod    = (float*)   (ws + O_DPOD);
  int*      cnt     = (int*)     (ws + O_CNT);
  int*      fill    = (int*)     (ws + O_FILL);
  int*      tstart  = (int*)     (ws + O_START);
  int*      nch     = (int*)     (ws + O_NCH);
  int4*     chunkT  = (int4*)    (ws + O_CHUNK);
  PointRec* rec     = (PointRec*)(ws + O_REC);
  int*      pairs   = (int*)     (ws + O_PAIRS);
  float*    wdc     = (float*)   (ws + O_WDC);
  float2*   kd      = (float2*)  (ws + O_KD);
  float*    gridR   = (float*)   (ws + O_GR);
  float2*   gridC   = (float2*)  (ws + O_GC);
  float2*   W1T     = (float2*)  (ws + O_REC);   // reuse record space (dead by then)

  const int PB = (KPTS + 255)/256;   // 1440

  gen_tables<<<4, 256, 0, stream>>>(tw512, tw1024, dpod);
  precompute_kb<<<PB, 256, 0, stream>>>(ktraj, rec, wdc);
  rowfft<<<NANG, 256, 0, stream>>>(sino, tw512, kd);

  // build tile lists (once per call; reused by all 11 scatters)
  hipMemsetAsync(cnt, 0, 8192, stream);          // cnt + fill (adjacent)
  count_tiles<<<PB, 256, 0, stream>>>(rec, cnt);
  scan_build<<<1, 1024, 0, stream>>>(cnt, tstart, chunkT, nch);
  fill_pairs<<<PB, 256, 0, stream>>>(rec, tstart, fill, pairs);

  for (int it = 0; it < NITER_DCOMP; ++it){
    hipMemsetAsync(gridR, 0, (size_t)GG*sizeof(float), stream);
    scatter_real_tiled<<<NSCATTER_BLOCKS, 256, 0, stream>>>(chunkT, nch, pairs, rec, wdc, gridR);
    gather_div<<<PB, 256, 0, stream>>>(rec, gridR, wdc);
  }

  hipMemsetAsync(gridC, 0, (size_t)GG*2*sizeof(float), stream);
  scatter_cplx_tiled<<<NSCATTER_BLOCKS, 256, 0, stream>>>(chunkT, nch, pairs, rec, kd, wdc, (float*)gridC);

  ifft_rows<<<G, 256, 0, stream>>>(gridC, tw1024, W1T);
  ifft_cols<<<WW, 256, 0, stream>>>(W1T, tw1024, dpod, out);
}